// Round 4
// baseline (238.993 us; speedup 1.0000x reference)
//
#include <hip/hip_runtime.h>

typedef unsigned short u16;
typedef unsigned int u32;
typedef unsigned char u8;
typedef signed char i8;

typedef int i32x4 __attribute__((ext_vector_type(4)));

// ---- async global->LDS, 16B per lane ----
__device__ inline void gld16(const i8* g, i8* l) {
    __builtin_amdgcn_global_load_lds((const __attribute__((address_space(1))) void*)g,
                                     (__attribute__((address_space(3))) void*)l,
                                     16, 0, 0);
}

// ---- fused prep: blocks [0,4096) quantize y rows, [4096,8192) quantize w tiles ----
// qy unit p = row*256 + t*8 + j holds logical chunk l = j ^ (row&7) of
// 128-k block t (16 i8, k = t*128 + l*16). sp[m] = s_m/127,
// tv[m] = 128*sum_k(y*rng) + sum_k(y*off).
// wq[n][k] = (i8)(w[k][n] - 128), transposed + swizzled, same unit layout.
__global__ __launch_bounds__(256) void prep_kernel(const float* __restrict__ y,
                                                   const float* __restrict__ rng,
                                                   const float* __restrict__ off,
                                                   const float* __restrict__ w,
                                                   uint4* __restrict__ qy,
                                                   uint4* __restrict__ wq,
                                                   float* __restrict__ sp,
                                                   float* __restrict__ tv) {
    __shared__ i8 tile[64][68];               // quant_w branch
    __shared__ float ra[4], rs1[4], rs2[4];   // quant_y branch
    const int tid = threadIdx.x;

    if (blockIdx.x < 4096) {
        // ---------------- quant_y ----------------
        const int row = blockIdx.x;
        const float* yr = y + (size_t)row * 4096;
        const int base = tid * 16;

        float ysr[16];
        float amax = 0.0f, s1 = 0.0f, s2 = 0.0f;
        #pragma unroll
        for (int ii = 0; ii < 4; ++ii) {
            float4 v = *(const float4*)&yr[base + ii * 4];
            float4 g = *(const float4*)&rng[base + ii * 4];
            float4 o = *(const float4*)&off[base + ii * 4];
            float p0 = v.x * g.x, p1 = v.y * g.y, p2 = v.z * g.z, p3 = v.w * g.w;
            ysr[ii * 4 + 0] = p0; ysr[ii * 4 + 1] = p1;
            ysr[ii * 4 + 2] = p2; ysr[ii * 4 + 3] = p3;
            s1 += p0 + p1 + p2 + p3;
            s2 += v.x * o.x + v.y * o.y + v.z * o.z + v.w * o.w;
            amax = fmaxf(amax, fmaxf(fmaxf(fabsf(p0), fabsf(p1)), fmaxf(fabsf(p2), fabsf(p3))));
        }
        #pragma unroll
        for (int d = 32; d > 0; d >>= 1) {
            amax = fmaxf(amax, __shfl_down(amax, d));
            s1 += __shfl_down(s1, d);
            s2 += __shfl_down(s2, d);
        }
        const int wv = tid >> 6;
        if ((tid & 63) == 0) { ra[wv] = amax; rs1[wv] = s1; rs2[wv] = s2; }
        __syncthreads();
        const float sm = fmaxf(fmaxf(ra[0], ra[1]), fmaxf(ra[2], ra[3]));
        const float inv = sm > 0.0f ? 127.0f / sm : 0.0f;

        u32 d[4];
        #pragma unroll
        for (int g = 0; g < 4; ++g) {
            u32 b0 = (u8)(i8)(int)rintf(ysr[g * 4 + 0] * inv);
            u32 b1 = (u8)(i8)(int)rintf(ysr[g * 4 + 1] * inv);
            u32 b2 = (u8)(i8)(int)rintf(ysr[g * 4 + 2] * inv);
            u32 b3 = (u8)(i8)(int)rintf(ysr[g * 4 + 3] * inv);
            d[g] = b0 | (b1 << 8) | (b2 << 16) | (b3 << 24);
        }
        const int j = (tid & 7) ^ (row & 7);
        qy[(size_t)row * 256 + (tid >> 3) * 8 + j] = make_uint4(d[0], d[1], d[2], d[3]);
        if (tid == 0) {
            sp[row] = sm / 127.0f;
            tv[row] = 128.0f * (rs1[0] + rs1[1] + rs1[2] + rs1[3])
                            + (rs2[0] + rs2[1] + rs2[2] + rs2[3]);
        }
    } else {
        // ---------------- quant_w ----------------
        const int bid = blockIdx.x - 4096;
        const int n0 = (bid & 63) * 64;
        const int k0 = (bid >> 6) * 64;
        const int c4 = tid & 15;
        const int r0 = tid >> 4;
        #pragma unroll
        for (int i = 0; i < 4; ++i) {
            int kk = r0 + i * 16;
            float4 v = *(const float4*)&w[(size_t)(k0 + kk) * 4096 + n0 + c4 * 4];
            u32 b0 = (u8)(i8)((int)v.x - 128);
            u32 b1 = (u8)(i8)((int)v.y - 128);
            u32 b2 = (u8)(i8)((int)v.z - 128);
            u32 b3 = (u8)(i8)((int)v.w - 128);
            *(u32*)&tile[kk][c4 * 4] = b0 | (b1 << 8) | (b2 << 16) | (b3 << 24);
        }
        __syncthreads();
        const int nl = tid >> 2;              // 0..63
        const int ci = tid & 3;               // 16-elem chunk within this 64-k tile
        const int l = ((k0 >> 4) & 7) + ci;   // logical chunk within 128-k block
        const int j = l ^ ((n0 + nl) & 7);
        u32 d[4];
        #pragma unroll
        for (int g = 0; g < 4; ++g) {
            int kl = ci * 16 + g * 4;
            d[g] = (u32)(u8)tile[kl + 0][nl] | ((u32)(u8)tile[kl + 1][nl] << 8)
                 | ((u32)(u8)tile[kl + 2][nl] << 16) | ((u32)(u8)tile[kl + 3][nl] << 24);
        }
        wq[(size_t)(n0 + nl) * 256 + (k0 >> 7) * 8 + j] = make_uint4(d[0], d[1], d[2], d[3]);
    }
}

// ---- GEMM: 256x256 tile, 8 waves (2Mx4N, 128x64 per wave), BK=128, double-buffered
// LDS (128KB). ONE barrier per K-tile: stage all 8 prefetch loads of t+1 at the
// top of tile t (sched_barrier-pinned; ~full tile in flight -> tile-end vmcnt(0)
// is free), then 24 ds_read_b128 + 64 MFMA with NO manual lgkmcnt — compiler
// emits counted lgkmcnt interleave (hides LDS reads under MFMA).
// Q[m][n] = sum_k qy[m][k]*wq[n][k] (exact i8->i32); out = sp[m]*Q + tv[m].
__global__ __launch_bounds__(512, 2) void gemm_kernel(const i8* __restrict__ qy,
                                                      const i8* __restrict__ wq,
                                                      const float* __restrict__ sp,
                                                      const float* __restrict__ tv,
                                                      float* __restrict__ out) {
    __shared__ i8 As[2][256 * 128];   // 2 x 32KB
    __shared__ i8 Bs[2][256 * 128];   // 2 x 32KB

    const int bid = blockIdx.x;       // 256 blocks = 16x16 tiles
    const int xcd = bid & 7;
    const int jj = bid >> 3;          // 0..31
    const int bn = (xcd * 2 + (jj & 1)) * 256;
    const int bm = (jj >> 1) * 256;

    const int tid = (int)threadIdx.x;
    const int lane = tid & 63;
    const int wv = tid >> 6;          // 0..7
    const int wm = (wv >> 2) * 128;   // 0 or 128
    const int wn = (wv & 3) * 64;     // 0,64,128,192
    const int r = lane & 15;
    const int q = lane >> 4;
    const int col0 = (q ^ (r & 7)) << 4;          // stored-unit byte offset, ks=0

    const int offA0 = (wm + r) * 128 + col0;      // + mi*2048 ; ks=1 -> ^64
    const int offB0 = (wn + r) * 128 + col0;      // + ni*2048
    const int offA1 = offA0 ^ 64;
    const int offB1 = offB0 ^ 64;

    // staging geometry: half-tile = 128 rows = 16 chunks of (8 rows x 128B);
    // wave wv copies chunks {wv, wv+8} (one per 128-row region).
    const int rsub = lane >> 3;
    const int jsub = lane & 7;
    // A-half h region rgn: global row = bm + h*64 + rgn*128 + wv*8 + rsub
    const i8* aP0 = qy + (size_t)(bm + wv * 8 + rsub) * 4096 + jsub * 16;
    // B-half h region rgn: global row = bn + (wv>>2)*64 + h*32 + (wv&3)*8 + rgn*128 + rsub
    const i8* bP0 = wq + (size_t)(bn + (wv >> 2) * 64 + (wv & 3) * 8 + rsub) * 4096 + jsub * 16;
    const int lAo = wv * 1024 + lane * 16;                      // + h*8192 + rgn*16384
    const int lBo = (wv >> 2) * 8192 + (wv & 3) * 1024 + lane * 16;  // + h*4096 + rgn*16384

    size_t koff = 0;

#define STAGE_A(WB, H) do {                                                   \
        gld16(aP0 + koff + (size_t)((H) * 64) * 4096,       &As[WB][lAo + (H) * 8192]);          \
        gld16(aP0 + koff + (size_t)((H) * 64 + 128) * 4096, &As[WB][lAo + (H) * 8192 + 16384]);  \
    } while (0)
#define STAGE_B(WB, H) do {                                                   \
        gld16(bP0 + koff + (size_t)((H) * 32) * 4096,       &Bs[WB][lBo + (H) * 4096]);          \
        gld16(bP0 + koff + (size_t)((H) * 32 + 128) * 4096, &Bs[WB][lBo + (H) * 4096 + 16384]);  \
    } while (0)
#define STAGE_ALL(WB) do {                                                    \
        STAGE_A(WB, 0); STAGE_A(WB, 1); STAGE_B(WB, 0); STAGE_B(WB, 1);       \
    } while (0)

    i32x4 acc[8][4] = {};
    i32x4 a[4][2], aa[4][2], b[4][2];

    // prologue: stage all of K-tile 0 into buffer 0
    STAGE_ALL(0);
    koff = 128;
    asm volatile("s_waitcnt vmcnt(0)" ::: "memory");
    __builtin_amdgcn_s_barrier();

#define RD_A4(RB, MB, DST)                                                    \
    _Pragma("unroll")                                                         \
    for (int mi = 0; mi < 4; ++mi) {                                          \
        DST[mi][0] = *(const i32x4*)&As[RB][offA0 + (MB + mi) * 2048];        \
        DST[mi][1] = *(const i32x4*)&As[RB][offA1 + (MB + mi) * 2048];        \
    }
#define RD_B4(RB)                                                             \
    _Pragma("unroll")                                                         \
    for (int ni = 0; ni < 4; ++ni) {                                          \
        b[ni][0] = *(const i32x4*)&Bs[RB][offB0 + ni * 2048];                 \
        b[ni][1] = *(const i32x4*)&Bs[RB][offB1 + ni * 2048];                 \
    }
#define MM32(MB, SRC)                                                         \
    _Pragma("unroll")                                                         \
    for (int mi = 0; mi < 4; ++mi) {                                          \
        _Pragma("unroll")                                                     \
        for (int ni = 0; ni < 4; ++ni) {                                      \
            acc[MB + mi][ni] = __builtin_amdgcn_mfma_i32_16x16x64_i8(         \
                SRC[mi][0], b[ni][0], acc[MB + mi][ni], 0, 0, 0);             \
            acc[MB + mi][ni] = __builtin_amdgcn_mfma_i32_16x16x64_i8(         \
                SRC[mi][1], b[ni][1], acc[MB + mi][ni], 0, 0, 0);             \
        }                                                                     \
    }

    // One barrier per K-tile. Entry invariant: tile t fully published in RB,
    // zero loads in flight.
#define KTILE(RB, WB, PF)                                                     \
    do {                                                                      \
        if (PF) { STAGE_ALL(WB); __builtin_amdgcn_sched_barrier(0); }         \
        RD_A4(RB, 0, a);                                                      \
        RD_B4(RB);                                                            \
        RD_A4(RB, 4, aa);                                                     \
        __builtin_amdgcn_s_setprio(1);                                        \
        MM32(0, a);                                                           \
        MM32(4, aa);                                                          \
        __builtin_amdgcn_s_setprio(0);                                        \
        asm volatile("s_waitcnt vmcnt(0)" ::: "memory");                      \
        __builtin_amdgcn_s_barrier();                                         \
        koff += 128;                                                          \
    } while (0)

    #pragma unroll 1
    for (int t = 0; t < 15; ++t) {
        KTILE(0, 1, 1);
        KTILE(1, 0, 1);
    }
    KTILE(0, 1, 1);   // K-tile 30, stages 31 -> buf1
    KTILE(1, 0, 0);   // K-tile 31, no prefetch

#undef KTILE
#undef MM32
#undef RD_B4
#undef RD_A4
#undef STAGE_ALL
#undef STAGE_B
#undef STAGE_A

    // C/D layout: n = lane&15, m = (lane>>4)*4 + reg (dtype-independent)
    #pragma unroll
    for (int mi = 0; mi < 8; ++mi) {
        #pragma unroll
        for (int rr = 0; rr < 4; ++rr) {
            const int gm = bm + wm + mi * 16 + q * 4 + rr;
            const float sc = sp[gm];
            const float tt = tv[gm];
            #pragma unroll
            for (int ni = 0; ni < 4; ++ni) {
                const int gn = bn + wn + ni * 16 + r;
                out[(size_t)gm * 4096 + gn] = sc * (float)acc[mi][ni][rr] + tt;
            }
        }
    }
}

extern "C" void kernel_launch(void* const* d_in, const int* in_sizes, int n_in,
                              void* d_out, int out_size, void* d_ws, size_t ws_size,
                              hipStream_t stream) {
    const float* y   = (const float*)d_in[0];   // (B,T,C) = 2*2048*4096
    const float* w   = (const float*)d_in[1];   // (C,N)   = 4096*4096
    const float* rng = (const float*)d_in[2];   // (1,1,C) = 4096
    const float* off = (const float*)d_in[3];   // (C,)    = 4096
    float* out = (float*)d_out;                 // (B,T,N) fp32

    i8* qy = (i8*)d_ws;                         // 16MB swizzled i8 [m][k]
    i8* wq = qy + (size_t)4096 * 4096;          // 16MB swizzled i8 [n][k]
    float* sp = (float*)(wq + (size_t)4096 * 4096);  // 16KB per-row scale
    float* tv = sp + 4096;                           // 16KB per-row additive term

    prep_kernel<<<8192, 256, 0, stream>>>(y, rng, off, w, (uint4*)qy, (uint4*)wq, sp, tv);
    gemm_kernel<<<256, 512, 0, stream>>>(qy, wq, sp, tv, out);
}

// Round 5
// 235.149 us; speedup vs baseline: 1.0163x; 1.0163x over previous
//
#include <hip/hip_runtime.h>

typedef unsigned short u16;
typedef unsigned int u32;
typedef unsigned char u8;
typedef signed char i8;

typedef int i32x4 __attribute__((ext_vector_type(4)));

// ---- async global->LDS, 16B per lane ----
__device__ inline void gld16(const i8* g, i8* l) {
    __builtin_amdgcn_global_load_lds((const __attribute__((address_space(1))) void*)g,
                                     (__attribute__((address_space(3))) void*)l,
                                     16, 0, 0);
}

// ---- fused prep: blocks [0,4096) quantize y rows, [4096,8192) quantize w tiles ----
// qy unit p = row*256 + t*8 + j holds logical chunk l = j ^ (row&7) of
// 128-k block t (16 i8, k = t*128 + l*16). sp[m] = s_m/127,
// tv[m] = 128*sum_k(y*rng) + sum_k(y*off).
// wq[n][k] = (i8)(w[k][n] - 128), transposed + swizzled, same unit layout.
__global__ __launch_bounds__(256) void prep_kernel(const float* __restrict__ y,
                                                   const float* __restrict__ rng,
                                                   const float* __restrict__ off,
                                                   const float* __restrict__ w,
                                                   uint4* __restrict__ qy,
                                                   uint4* __restrict__ wq,
                                                   float* __restrict__ sp,
                                                   float* __restrict__ tv) {
    __shared__ i8 tile[64][68];               // quant_w branch
    __shared__ float ra[4], rs1[4], rs2[4];   // quant_y branch
    const int tid = threadIdx.x;

    if (blockIdx.x < 4096) {
        // ---------------- quant_y ----------------
        const int row = blockIdx.x;
        const float* yr = y + (size_t)row * 4096;
        const int base = tid * 16;

        float ysr[16];
        float amax = 0.0f, s1 = 0.0f, s2 = 0.0f;
        #pragma unroll
        for (int ii = 0; ii < 4; ++ii) {
            float4 v = *(const float4*)&yr[base + ii * 4];
            float4 g = *(const float4*)&rng[base + ii * 4];
            float4 o = *(const float4*)&off[base + ii * 4];
            float p0 = v.x * g.x, p1 = v.y * g.y, p2 = v.z * g.z, p3 = v.w * g.w;
            ysr[ii * 4 + 0] = p0; ysr[ii * 4 + 1] = p1;
            ysr[ii * 4 + 2] = p2; ysr[ii * 4 + 3] = p3;
            s1 += p0 + p1 + p2 + p3;
            s2 += v.x * o.x + v.y * o.y + v.z * o.z + v.w * o.w;
            amax = fmaxf(amax, fmaxf(fmaxf(fabsf(p0), fabsf(p1)), fmaxf(fabsf(p2), fabsf(p3))));
        }
        #pragma unroll
        for (int d = 32; d > 0; d >>= 1) {
            amax = fmaxf(amax, __shfl_down(amax, d));
            s1 += __shfl_down(s1, d);
            s2 += __shfl_down(s2, d);
        }
        const int wv = tid >> 6;
        if ((tid & 63) == 0) { ra[wv] = amax; rs1[wv] = s1; rs2[wv] = s2; }
        __syncthreads();
        const float sm = fmaxf(fmaxf(ra[0], ra[1]), fmaxf(ra[2], ra[3]));
        const float inv = sm > 0.0f ? 127.0f / sm : 0.0f;

        u32 d[4];
        #pragma unroll
        for (int g = 0; g < 4; ++g) {
            u32 b0 = (u8)(i8)(int)rintf(ysr[g * 4 + 0] * inv);
            u32 b1 = (u8)(i8)(int)rintf(ysr[g * 4 + 1] * inv);
            u32 b2 = (u8)(i8)(int)rintf(ysr[g * 4 + 2] * inv);
            u32 b3 = (u8)(i8)(int)rintf(ysr[g * 4 + 3] * inv);
            d[g] = b0 | (b1 << 8) | (b2 << 16) | (b3 << 24);
        }
        const int j = (tid & 7) ^ (row & 7);
        qy[(size_t)row * 256 + (tid >> 3) * 8 + j] = make_uint4(d[0], d[1], d[2], d[3]);
        if (tid == 0) {
            sp[row] = sm / 127.0f;
            tv[row] = 128.0f * (rs1[0] + rs1[1] + rs1[2] + rs1[3])
                            + (rs2[0] + rs2[1] + rs2[2] + rs2[3]);
        }
    } else {
        // ---------------- quant_w ----------------
        const int bid = blockIdx.x - 4096;
        const int n0 = (bid & 63) * 64;
        const int k0 = (bid >> 6) * 64;
        const int c4 = tid & 15;
        const int r0 = tid >> 4;
        #pragma unroll
        for (int i = 0; i < 4; ++i) {
            int kk = r0 + i * 16;
            float4 v = *(const float4*)&w[(size_t)(k0 + kk) * 4096 + n0 + c4 * 4];
            u32 b0 = (u8)(i8)((int)v.x - 128);
            u32 b1 = (u8)(i8)((int)v.y - 128);
            u32 b2 = (u8)(i8)((int)v.z - 128);
            u32 b3 = (u8)(i8)((int)v.w - 128);
            *(u32*)&tile[kk][c4 * 4] = b0 | (b1 << 8) | (b2 << 16) | (b3 << 24);
        }
        __syncthreads();
        const int nl = tid >> 2;              // 0..63
        const int ci = tid & 3;               // 16-elem chunk within this 64-k tile
        const int l = ((k0 >> 4) & 7) + ci;   // logical chunk within 128-k block
        const int j = l ^ ((n0 + nl) & 7);
        u32 d[4];
        #pragma unroll
        for (int g = 0; g < 4; ++g) {
            int kl = ci * 16 + g * 4;
            d[g] = (u32)(u8)tile[kl + 0][nl] | ((u32)(u8)tile[kl + 1][nl] << 8)
                 | ((u32)(u8)tile[kl + 2][nl] << 16) | ((u32)(u8)tile[kl + 3][nl] << 24);
        }
        wq[(size_t)(n0 + nl) * 256 + (k0 >> 7) * 8 + j] = make_uint4(d[0], d[1], d[2], d[3]);
    }
}

// ---- GEMM: 256x256 tile, 8 waves (2Mx4N, 128x64 per wave), BK=128, double-buffered
// LDS (128KB). R3 skeleton (2 barriers/tile, counted vmcnt(4)/vmcnt(2), stages
// issued AFTER ds_reads) + counted-lgkmcnt clusters: per half, issue ks0+ks1
// reads in queue order, lgkmcnt(8/4) -> MFMA ks0 cluster overlaps ks1 reads in
// the LDS pipe, lgkmcnt(0) -> ks1 cluster.
// Q[m][n] = sum_k qy[m][k]*wq[n][k] (exact i8->i32); out = sp[m]*Q + tv[m].
__global__ __launch_bounds__(512, 2) void gemm_kernel(const i8* __restrict__ qy,
                                                      const i8* __restrict__ wq,
                                                      const float* __restrict__ sp,
                                                      const float* __restrict__ tv,
                                                      float* __restrict__ out) {
    __shared__ i8 As[2][256 * 128];   // 2 x 32KB
    __shared__ i8 Bs[2][256 * 128];   // 2 x 32KB

    const int bid = blockIdx.x;       // 256 blocks = 16x16 tiles
    const int xcd = bid & 7;
    const int jj = bid >> 3;          // 0..31
    const int bn = (xcd * 2 + (jj & 1)) * 256;
    const int bm = (jj >> 1) * 256;

    const int tid = (int)threadIdx.x;
    const int lane = tid & 63;
    const int wv = tid >> 6;          // 0..7
    const int wm = (wv >> 2) * 128;   // 0 or 128
    const int wn = (wv & 3) * 64;     // 0,64,128,192
    const int r = lane & 15;
    const int q = lane >> 4;
    const int col0 = (q ^ (r & 7)) << 4;          // stored-unit byte offset, ks=0

    const int offA0 = (wm + r) * 128 + col0;      // + mi*2048 ; ks=1 -> ^64
    const int offB0 = (wn + r) * 128 + col0;      // + ni*2048
    const int offA1 = offA0 ^ 64;
    const int offB1 = offB0 ^ 64;

    // staging geometry: half-tile = 128 rows = 16 chunks of (8 rows x 128B);
    // wave wv copies chunks {wv, wv+8} (one per 128-row region).
    const int rsub = lane >> 3;
    const int jsub = lane & 7;
    // A-half h region rgn: global row = bm + h*64 + rgn*128 + wv*8 + rsub
    const i8* aP0 = qy + (size_t)(bm + wv * 8 + rsub) * 4096 + jsub * 16;
    // B-half h region rgn: global row = bn + (wv>>2)*64 + h*32 + (wv&3)*8 + rgn*128 + rsub
    const i8* bP0 = wq + (size_t)(bn + (wv >> 2) * 64 + (wv & 3) * 8 + rsub) * 4096 + jsub * 16;
    const int lAo = wv * 1024 + lane * 16;                      // + h*8192 + rgn*16384
    const int lBo = (wv >> 2) * 8192 + (wv & 3) * 1024 + lane * 16;  // + h*4096 + rgn*16384

    size_t koff = 0;

#define STAGE_A(WB, H) do {                                                   \
        gld16(aP0 + koff + (size_t)((H) * 64) * 4096,       &As[WB][lAo + (H) * 8192]);          \
        gld16(aP0 + koff + (size_t)((H) * 64 + 128) * 4096, &As[WB][lAo + (H) * 8192 + 16384]);  \
    } while (0)
#define STAGE_B(WB, H) do {                                                   \
        gld16(bP0 + koff + (size_t)((H) * 32) * 4096,       &Bs[WB][lBo + (H) * 4096]);          \
        gld16(bP0 + koff + (size_t)((H) * 32 + 128) * 4096, &Bs[WB][lBo + (H) * 4096 + 16384]);  \
    } while (0)

    i32x4 acc[8][4] = {};
    i32x4 a[4][2], aa[4][2], b[4][2];

    // prologue: stage all 4 halves of K-tile 0 into buffer 0, queue order
    // A-h0, B-h0, B-h1, [pin] A-h1; drain to 2 (A-h1 still in flight).
    STAGE_A(0, 0); STAGE_B(0, 0); STAGE_B(0, 1);
    __builtin_amdgcn_sched_barrier(0);
    STAGE_A(0, 1);
    koff = 128;
    asm volatile("s_waitcnt vmcnt(2)" ::: "memory");
    __builtin_amdgcn_s_barrier();

#define RD_A4K(RB, MB, DST, KS)                                               \
    _Pragma("unroll")                                                         \
    for (int mi = 0; mi < 4; ++mi) {                                          \
        DST[mi][KS] = *(const i32x4*)&As[RB][((KS) ? offA1 : offA0) + (MB + mi) * 2048]; \
    }
#define RD_B4K(RB, KS)                                                        \
    _Pragma("unroll")                                                         \
    for (int ni = 0; ni < 4; ++ni) {                                          \
        b[ni][KS] = *(const i32x4*)&Bs[RB][((KS) ? offB1 : offB0) + ni * 2048]; \
    }
#define MM16(MB, SRC, KS)                                                     \
    _Pragma("unroll")                                                         \
    for (int mi = 0; mi < 4; ++mi) {                                          \
        _Pragma("unroll")                                                     \
        for (int ni = 0; ni < 4; ++ni) {                                      \
            acc[MB + mi][ni] = __builtin_amdgcn_mfma_i32_16x16x64_i8(         \
                SRC[mi][KS], b[ni][KS], acc[MB + mi][ni], 0, 0, 0);           \
        }                                                                     \
    }

    // Steady-state entry invariant: queue = {A-h1(t)} (2 loads) in flight;
    // A-h0(t), B-h0(t), B-h1(t) published (landed + barrier).
#define KTILE(RB, WB, PF)                                                     \
    do {                                                                      \
        /* ---- half 1: mi0-3 x ni0-3, ks0 then ks1 ---- */                   \
        RD_A4K(RB, 0, a, 0);                                                  \
        RD_B4K(RB, 0);           /* first 8 ds_reads = ks0 frags */           \
        RD_A4K(RB, 0, a, 1);                                                  \
        RD_B4K(RB, 1);           /* next 8 = ks1 frags */                     \
        if (PF) { STAGE_A(WB, 0); STAGE_B(WB, 0); }                           \
        __builtin_amdgcn_s_setprio(1);                                        \
        asm volatile("s_waitcnt lgkmcnt(8)" ::: "memory");  /* ks0 landed */  \
        __builtin_amdgcn_sched_barrier(0);                                    \
        MM16(0, a, 0);           /* overlaps ks1 reads in LDS pipe */         \
        asm volatile("s_waitcnt lgkmcnt(0)" ::: "memory");                    \
        __builtin_amdgcn_sched_barrier(0);                                    \
        MM16(0, a, 1);                                                        \
        __builtin_amdgcn_s_setprio(0);                                        \
        if (PF) asm volatile("s_waitcnt vmcnt(4)" ::: "memory");  /* A-h1(t) landed */ \
        else    asm volatile("s_waitcnt vmcnt(0)" ::: "memory");              \
        __builtin_amdgcn_s_barrier();                                         \
        /* ---- half 2: mi4-7 (b[] held in regs) ---- */                      \
        RD_A4K(RB, 4, aa, 0);                                                 \
        RD_A4K(RB, 4, aa, 1);                                                 \
        if (PF) { STAGE_B(WB, 1); __builtin_amdgcn_sched_barrier(0); STAGE_A(WB, 1); } \
        __builtin_amdgcn_s_setprio(1);                                        \
        asm volatile("s_waitcnt lgkmcnt(4)" ::: "memory");  /* aa-ks0 landed */ \
        __builtin_amdgcn_sched_barrier(0);                                    \
        MM16(4, aa, 0);          /* overlaps aa-ks1 reads */                  \
        asm volatile("s_waitcnt lgkmcnt(0)" ::: "memory");                    \
        __builtin_amdgcn_sched_barrier(0);                                    \
        MM16(4, aa, 1);                                                       \
        __builtin_amdgcn_s_setprio(0);                                        \
        if (PF) asm volatile("s_waitcnt vmcnt(2)" ::: "memory");  /* t+1: A-h0,B-h0,B-h1 landed */ \
        else    asm volatile("s_waitcnt vmcnt(0)" ::: "memory");              \
        __builtin_amdgcn_s_barrier();                                         \
        koff += 128;                                                          \
    } while (0)

    #pragma unroll 1
    for (int t = 0; t < 15; ++t) {
        KTILE(0, 1, 1);
        KTILE(1, 0, 1);
    }
    KTILE(0, 1, 1);   // K-tile 30, stages 31 -> buf1
    KTILE(1, 0, 0);   // K-tile 31, no prefetch (vmcnt(0) drains leftovers)

#undef KTILE
#undef MM16
#undef RD_B4K
#undef RD_A4K
#undef STAGE_B
#undef STAGE_A

    // C/D layout: n = lane&15, m = (lane>>4)*4 + reg (dtype-independent)
    #pragma unroll
    for (int mi = 0; mi < 8; ++mi) {
        #pragma unroll
        for (int rr = 0; rr < 4; ++rr) {
            const int gm = bm + wm + mi * 16 + q * 4 + rr;
            const float sc = sp[gm];
            const float tt = tv[gm];
            #pragma unroll
            for (int ni = 0; ni < 4; ++ni) {
                const int gn = bn + wn + ni * 16 + r;
                out[(size_t)gm * 4096 + gn] = sc * (float)acc[mi][ni][rr] + tt;
            }
        }
    }
}

extern "C" void kernel_launch(void* const* d_in, const int* in_sizes, int n_in,
                              void* d_out, int out_size, void* d_ws, size_t ws_size,
                              hipStream_t stream) {
    const float* y   = (const float*)d_in[0];   // (B,T,C) = 2*2048*4096
    const float* w   = (const float*)d_in[1];   // (C,N)   = 4096*4096
    const float* rng = (const float*)d_in[2];   // (1,1,C) = 4096
    const float* off = (const float*)d_in[3];   // (C,)    = 4096
    float* out = (float*)d_out;                 // (B,T,N) fp32

    i8* qy = (i8*)d_ws;                         // 16MB swizzled i8 [m][k]
    i8* wq = qy + (size_t)4096 * 4096;          // 16MB swizzled i8 [n][k]
    float* sp = (float*)(wq + (size_t)4096 * 4096);  // 16KB per-row scale
    float* tv = sp + 4096;                           // 16KB per-row additive term

    prep_kernel<<<8192, 256, 0, stream>>>(y, rng, off, w, (uint4*)qy, (uint4*)wq, sp, tv);
    gemm_kernel<<<256, 512, 0, stream>>>(qy, wq, sp, tv, out);
}

// Round 7
// 230.452 us; speedup vs baseline: 1.0371x; 1.0204x over previous
//
#include <hip/hip_runtime.h>

typedef unsigned short u16;
typedef unsigned int u32;
typedef unsigned char u8;
typedef signed char i8;

typedef int i32x4 __attribute__((ext_vector_type(4)));

// ---- async global->LDS, 16B per lane ----
__device__ inline void gld16(const i8* g, i8* l) {
    __builtin_amdgcn_global_load_lds((const __attribute__((address_space(1))) void*)g,
                                     (__attribute__((address_space(3))) void*)l,
                                     16, 0, 0);
}

// ---- fused prep: blocks [0,4096) quantize y rows, [4096,8192) quantize w tiles ----
// qy unit p = row*256 + t*8 + j holds logical chunk l = j ^ (row&7) of
// 128-k block t (16 i8, k = t*128 + l*16). sp[m] = s_m/127,
// tv[m] = 128*sum_k(y*rng) + sum_k(y*off).
// wq[n][k] = (i8)(w[k][n] - 128), transposed + swizzled, same unit layout.
__global__ __launch_bounds__(256) void prep_kernel(const float* __restrict__ y,
                                                   const float* __restrict__ rng,
                                                   const float* __restrict__ off,
                                                   const float* __restrict__ w,
                                                   uint4* __restrict__ qy,
                                                   uint4* __restrict__ wq,
                                                   float* __restrict__ sp,
                                                   float* __restrict__ tv) {
    __shared__ i8 tile[64][68];               // quant_w branch
    __shared__ float ra[4], rs1[4], rs2[4];   // quant_y branch
    const int tid = threadIdx.x;

    if (blockIdx.x < 4096) {
        // ---------------- quant_y ----------------
        const int row = blockIdx.x;
        const float* yr = y + (size_t)row * 4096;
        const int base = tid * 16;

        float ysr[16];
        float amax = 0.0f, s1 = 0.0f, s2 = 0.0f;
        #pragma unroll
        for (int ii = 0; ii < 4; ++ii) {
            float4 v = *(const float4*)&yr[base + ii * 4];
            float4 g = *(const float4*)&rng[base + ii * 4];
            float4 o = *(const float4*)&off[base + ii * 4];
            float p0 = v.x * g.x, p1 = v.y * g.y, p2 = v.z * g.z, p3 = v.w * g.w;
            ysr[ii * 4 + 0] = p0; ysr[ii * 4 + 1] = p1;
            ysr[ii * 4 + 2] = p2; ysr[ii * 4 + 3] = p3;
            s1 += p0 + p1 + p2 + p3;
            s2 += v.x * o.x + v.y * o.y + v.z * o.z + v.w * o.w;
            amax = fmaxf(amax, fmaxf(fmaxf(fabsf(p0), fabsf(p1)), fmaxf(fabsf(p2), fabsf(p3))));
        }
        #pragma unroll
        for (int d = 32; d > 0; d >>= 1) {
            amax = fmaxf(amax, __shfl_down(amax, d));
            s1 += __shfl_down(s1, d);
            s2 += __shfl_down(s2, d);
        }
        const int wv = tid >> 6;
        if ((tid & 63) == 0) { ra[wv] = amax; rs1[wv] = s1; rs2[wv] = s2; }
        __syncthreads();
        const float sm = fmaxf(fmaxf(ra[0], ra[1]), fmaxf(ra[2], ra[3]));
        const float inv = sm > 0.0f ? 127.0f / sm : 0.0f;

        u32 d[4];
        #pragma unroll
        for (int g = 0; g < 4; ++g) {
            u32 b0 = (u8)(i8)(int)rintf(ysr[g * 4 + 0] * inv);
            u32 b1 = (u8)(i8)(int)rintf(ysr[g * 4 + 1] * inv);
            u32 b2 = (u8)(i8)(int)rintf(ysr[g * 4 + 2] * inv);
            u32 b3 = (u8)(i8)(int)rintf(ysr[g * 4 + 3] * inv);
            d[g] = b0 | (b1 << 8) | (b2 << 16) | (b3 << 24);
        }
        const int j = (tid & 7) ^ (row & 7);
        qy[(size_t)row * 256 + (tid >> 3) * 8 + j] = make_uint4(d[0], d[1], d[2], d[3]);
        if (tid == 0) {
            sp[row] = sm / 127.0f;
            tv[row] = 128.0f * (rs1[0] + rs1[1] + rs1[2] + rs1[3])
                            + (rs2[0] + rs2[1] + rs2[2] + rs2[3]);
        }
    } else {
        // ---------------- quant_w ----------------
        const int bid = blockIdx.x - 4096;
        const int n0 = (bid & 63) * 64;
        const int k0 = (bid >> 6) * 64;
        const int c4 = tid & 15;
        const int r0 = tid >> 4;
        #pragma unroll
        for (int i = 0; i < 4; ++i) {
            int kk = r0 + i * 16;
            float4 v = *(const float4*)&w[(size_t)(k0 + kk) * 4096 + n0 + c4 * 4];
            u32 b0 = (u8)(i8)((int)v.x - 128);
            u32 b1 = (u8)(i8)((int)v.y - 128);
            u32 b2 = (u8)(i8)((int)v.z - 128);
            u32 b3 = (u8)(i8)((int)v.w - 128);
            *(u32*)&tile[kk][c4 * 4] = b0 | (b1 << 8) | (b2 << 16) | (b3 << 24);
        }
        __syncthreads();
        const int nl = tid >> 2;              // 0..63
        const int ci = tid & 3;               // 16-elem chunk within this 64-k tile
        const int l = ((k0 >> 4) & 7) + ci;   // logical chunk within 128-k block
        const int j = l ^ ((n0 + nl) & 7);
        u32 d[4];
        #pragma unroll
        for (int g = 0; g < 4; ++g) {
            int kl = ci * 16 + g * 4;
            d[g] = (u32)(u8)tile[kl + 0][nl] | ((u32)(u8)tile[kl + 1][nl] << 8)
                 | ((u32)(u8)tile[kl + 2][nl] << 16) | ((u32)(u8)tile[kl + 3][nl] << 24);
        }
        wq[(size_t)(n0 + nl) * 256 + (k0 >> 7) * 8 + j] = make_uint4(d[0], d[1], d[2], d[3]);
    }
}

// ---- GEMM: 256x256 tile, 8 waves (2Mx4N, 128x64 per wave), BK=128, double-buffered
// LDS (128KB). ONE barrier per K-tile (wave drift => cross-wave LDS||MFMA overlap):
// issue h1 reads (ks0,ks1 clusters pinned) -> stage ALL of t+1 (8 gld16, drained
// ~1500cy later at tile end) -> counted lgkm ladder: lgkm(8) MM(h1,ks0) | issue aa
// clusters | lgkm(8) MM(h1,ks1) | lgkm(4) MM(h2,ks0) | lgkm(0) MM(h2,ks1) ->
// vmcnt(0)+barrier.
// Q[m][n] = sum_k qy[m][k]*wq[n][k] (exact i8->i32); out = sp[m]*Q + tv[m].
__global__ __launch_bounds__(512, 2) void gemm_kernel(const i8* __restrict__ qy,
                                                      const i8* __restrict__ wq,
                                                      const float* __restrict__ sp,
                                                      const float* __restrict__ tv,
                                                      float* __restrict__ out) {
    __shared__ i8 As[2][256 * 128];   // 2 x 32KB
    __shared__ i8 Bs[2][256 * 128];   // 2 x 32KB

    const int bid = blockIdx.x;       // 256 blocks = 16x16 tiles
    const int xcd = bid & 7;
    const int jj = bid >> 3;          // 0..31
    const int bn = (xcd * 2 + (jj & 1)) * 256;
    const int bm = (jj >> 1) * 256;

    const int tid = (int)threadIdx.x;
    const int lane = tid & 63;
    const int wv = tid >> 6;          // 0..7
    const int wm = (wv >> 2) * 128;   // 0 or 128
    const int wn = (wv & 3) * 64;     // 0,64,128,192
    const int r = lane & 15;
    const int q = lane >> 4;
    const int col0 = (q ^ (r & 7)) << 4;          // stored-unit byte offset, ks=0

    const int offA0 = (wm + r) * 128 + col0;      // + mi*2048 ; ks=1 -> ^64
    const int offB0 = (wn + r) * 128 + col0;      // + ni*2048
    const int offA1 = offA0 ^ 64;
    const int offB1 = offB0 ^ 64;

    // staging geometry: half-tile = 128 rows = 16 chunks of (8 rows x 128B);
    // wave wv copies chunks {wv, wv+8} (one per 128-row region).
    const int rsub = lane >> 3;
    const int jsub = lane & 7;
    // A-half h region rgn: global row = bm + h*64 + rgn*128 + wv*8 + rsub
    const i8* aP0 = qy + (size_t)(bm + wv * 8 + rsub) * 4096 + jsub * 16;
    // B-half h region rgn: global row = bn + (wv>>2)*64 + h*32 + (wv&3)*8 + rgn*128 + rsub
    const i8* bP0 = wq + (size_t)(bn + (wv >> 2) * 64 + (wv & 3) * 8 + rsub) * 4096 + jsub * 16;
    const int lAo = wv * 1024 + lane * 16;                      // + h*8192 + rgn*16384
    const int lBo = (wv >> 2) * 8192 + (wv & 3) * 1024 + lane * 16;  // + h*4096 + rgn*16384

    size_t koff = 0;

#define STAGE_A(WB, H) do {                                                   \
        gld16(aP0 + koff + (size_t)((H) * 64) * 4096,       &As[WB][lAo + (H) * 8192]);          \
        gld16(aP0 + koff + (size_t)((H) * 64 + 128) * 4096, &As[WB][lAo + (H) * 8192 + 16384]);  \
    } while (0)
#define STAGE_B(WB, H) do {                                                   \
        gld16(bP0 + koff + (size_t)((H) * 32) * 4096,       &Bs[WB][lBo + (H) * 4096]);          \
        gld16(bP0 + koff + (size_t)((H) * 32 + 128) * 4096, &Bs[WB][lBo + (H) * 4096 + 16384]);  \
    } while (0)

    i32x4 acc[8][4] = {};
    i32x4 a[4][2], aa[4][2], b[4][2];

    // prologue: stage all 4 halves of K-tile 0 into buffer 0, drain fully.
    STAGE_A(0, 0); STAGE_B(0, 0); STAGE_B(0, 1); STAGE_A(0, 1);
    koff = 128;
    asm volatile("s_waitcnt vmcnt(0)" ::: "memory");
    __builtin_amdgcn_s_barrier();

#define SB __builtin_amdgcn_sched_barrier(0)

#define RD_A4K(RB, MB, DST, KS)                                               \
    _Pragma("unroll")                                                         \
    for (int mi = 0; mi < 4; ++mi) {                                          \
        DST[mi][KS] = *(const i32x4*)&As[RB][((KS) ? offA1 : offA0) + (MB + mi) * 2048]; \
    }
#define RD_B4K(RB, KS)                                                        \
    _Pragma("unroll")                                                         \
    for (int ni = 0; ni < 4; ++ni) {                                          \
        b[ni][KS] = *(const i32x4*)&Bs[RB][((KS) ? offB1 : offB0) + ni * 2048]; \
    }
#define MM16(MB, SRC, KS)                                                     \
    _Pragma("unroll")                                                         \
    for (int mi = 0; mi < 4; ++mi) {                                          \
        _Pragma("unroll")                                                     \
        for (int ni = 0; ni < 4; ++ni) {                                      \
            acc[MB + mi][ni] = __builtin_amdgcn_mfma_i32_16x16x64_i8(         \
                SRC[mi][KS], b[ni][KS], acc[MB + mi][ni], 0, 0, 0);           \
        }                                                                     \
    }

    // Entry invariant: tile t fully published in RB; vm queue empty.
#define KTILE(RB, WB, PF)                                                     \
    do {                                                                      \
        /* C1: h1 ks0 cluster (8 reads) */                                    \
        RD_A4K(RB, 0, a, 0); RD_B4K(RB, 0); SB;                               \
        /* C2: h1 ks1 cluster (8 reads) */                                    \
        RD_A4K(RB, 0, a, 1); RD_B4K(RB, 1); SB;                               \
        /* stage ALL of t+1 (8 gld16) — drained at tile end, ~1500cy away */  \
        if (PF) { STAGE_A(WB, 0); STAGE_B(WB, 0); STAGE_B(WB, 1); STAGE_A(WB, 1); } \
        SB;                                                                   \
        __builtin_amdgcn_s_setprio(1);                                        \
        asm volatile("s_waitcnt lgkmcnt(8)" ::: "memory"); SB;  /* C1 done */ \
        MM16(0, a, 0); SB;                                                    \
        /* C3/C4: h2 clusters (4+4 reads), overlap MM of C2 */                \
        RD_A4K(RB, 4, aa, 0); SB;                                             \
        RD_A4K(RB, 4, aa, 1); SB;                                             \
        asm volatile("s_waitcnt lgkmcnt(8)" ::: "memory"); SB;  /* C2 done */ \
        MM16(0, a, 1); SB;                                                    \
        asm volatile("s_waitcnt lgkmcnt(4)" ::: "memory"); SB;  /* C3 done */ \
        MM16(4, aa, 0); SB;                                                   \
        asm volatile("s_waitcnt lgkmcnt(0)" ::: "memory"); SB;  /* C4 done */ \
        MM16(4, aa, 1);                                                       \
        __builtin_amdgcn_s_setprio(0);                                        \
        asm volatile("s_waitcnt vmcnt(0)" ::: "memory");                      \
        __builtin_amdgcn_s_barrier();                                         \
        koff += 128;                                                          \
    } while (0)

    #pragma unroll 1
    for (int t = 0; t < 15; ++t) {
        KTILE(0, 1, 1);
        KTILE(1, 0, 1);
    }
    KTILE(0, 1, 1);   // K-tile 30, stages 31 -> buf1
    KTILE(1, 0, 0);   // K-tile 31, no prefetch

#undef KTILE
#undef MM16
#undef RD_B4K
#undef RD_A4K
#undef SB
#undef STAGE_B
#undef STAGE_A

    // C/D layout: n = lane&15, m = (lane>>4)*4 + reg (dtype-independent)
    #pragma unroll
    for (int mi = 0; mi < 8; ++mi) {
        #pragma unroll
        for (int rr = 0; rr < 4; ++rr) {
            const int gm = bm + wm + mi * 16 + q * 4 + rr;
            const float sc = sp[gm];
            const float tt = tv[gm];
            #pragma unroll
            for (int ni = 0; ni < 4; ++ni) {
                const int gn = bn + wn + ni * 16 + r;
                out[(size_t)gm * 4096 + gn] = sc * (float)acc[mi][ni][rr] + tt;
            }
        }
    }
}

extern "C" void kernel_launch(void* const* d_in, const int* in_sizes, int n_in,
                              void* d_out, int out_size, void* d_ws, size_t ws_size,
                              hipStream_t stream) {
    const float* y   = (const float*)d_in[0];   // (B,T,C) = 2*2048*4096
    const float* w   = (const float*)d_in[1];   // (C,N)   = 4096*4096
    const float* rng = (const float*)d_in[2];   // (1,1,C) = 4096
    const float* off = (const float*)d_in[3];   // (C,)    = 4096
    float* out = (float*)d_out;                 // (B,T,N) fp32

    i8* qy = (i8*)d_ws;                         // 16MB swizzled i8 [m][k]
    i8* wq = qy + (size_t)4096 * 4096;          // 16MB swizzled i8 [n][k]
    float* sp = (float*)(wq + (size_t)4096 * 4096);  // 16KB per-row scale
    float* tv = sp + 4096;                           // 16KB per-row additive term

    prep_kernel<<<8192, 256, 0, stream>>>(y, rng, off, w, (uint4*)qy, (uint4*)wq, sp, tv);
    gemm_kernel<<<256, 512, 0, stream>>>(qy, wq, sp, tv, out);
}